// Round 4
// baseline (105.177 us; speedup 1.0000x reference)
//
#include <hip/hip_runtime.h>
#include <hip/hip_bf16.h>
#include <math.h>

#define E_ 128
#define H_ 128
#define B_ 8
#define U_ 128
#define T_ 256

typedef short short8 __attribute__((ext_vector_type(8)));
typedef unsigned short ushortx8 __attribute__((ext_vector_type(8)));
typedef float floatx4 __attribute__((ext_vector_type(4)));

__device__ __forceinline__ unsigned short f2bf(float f) {
    union { __hip_bfloat16 b; unsigned short u; } cv;
    cv.b = __float2bfloat16(f);
    return cv.u;
}
__device__ __forceinline__ float bf2f(unsigned short u) {
    union { unsigned int u; float f; } cv;
    cv.u = ((unsigned int)u) << 16;
    return cv.f;
}

// Swizzled LDS index for [128][128] bf16 tiles, 8-element column blocks.
// Readers fetch (row, cblk) with row&15 == l16 -> banks spread, 2-way only (free).
__device__ __forceinline__ int sw(int row, int cblk) {
    return row * 128 + (((cblk ^ (row & 15)) << 3));
}

// tanh-form gelu: x * sigmoid(1.59577x + 0.0713548x^3); |err| vs erf-gelu <~3e-4.
// exp2-folded coefficients (x * log2e).
__device__ __forceinline__ float gelu_fast(float x) {
    float x2 = x * x;
    float p = x * __builtin_fmaf(x2, 0.1029407583f, 2.3022586210f);
    float e = __builtin_amdgcn_exp2f(-p);
    return x * __builtin_amdgcn_rcpf(1.0f + e);
}

// ---------------- Stage 1 (one kernel, 36 blocks) ---------------------------
// blk 0..7  : hu[128 rows] = ue_tile @ W1u  (bf16 MFMA, fp32 out)
// blk 8..23 : ht[128 rows] = te_tile @ W1t  (bf16 MFMA, bf16 out)
// blk 24..27: gu[2 rows]   = ge @ W1g + b1  (fp32 VALU)
// blk 28..35: w2t bf16 transpose
__global__ __launch_bounds__(256) void stage1_kernel(
    const float* __restrict__ ue, const float* __restrict__ te,
    const float* __restrict__ ge, const float* __restrict__ W1,
    const float* __restrict__ b1, const float* __restrict__ W2,
    float* __restrict__ hu_ws, unsigned short* __restrict__ ht_bf,
    float* __restrict__ gu_ws, unsigned short* __restrict__ w2t_ws)
{
    const int blk = blockIdx.x;
    const int tid = threadIdx.x;

    if (blk < 24) {
        __shared__ unsigned short a_s[128 * 128];
        __shared__ unsigned short w_s[128 * 128];
        const float* __restrict__ A;
        const float* __restrict__ W;
        const bool is_ue = (blk < 8);
        if (is_ue) { A = ue + (size_t)blk * 128 * E_;       W = W1; }
        else       { A = te + (size_t)(blk - 8) * 128 * E_; W = W1 + E_ * H_; }

        // stage A: coalesced float4, bf16, swizzled rows
        const float4* __restrict__ Av = (const float4*)A;
        #pragma unroll
        for (int i = 0; i < 16; i++) {
            const int v = tid + i * 256;
            const int row = v >> 5, c4 = (v & 31) * 4;
            const float4 f = Av[v];
            ushort4 u4 = make_ushort4(f2bf(f.x), f2bf(f.y), f2bf(f.z), f2bf(f.w));
            *(ushort4*)(&a_s[sw(row, c4 >> 3) + (c4 & 7)]) = u4;
        }
        // stage W transposed: read [k][n] float4, scatter bf16 (<=4-way conflict)
        const float4* __restrict__ Wv = (const float4*)W;
        #pragma unroll
        for (int i = 0; i < 16; i++) {
            const int v = tid + i * 256;
            const int k = v >> 5, n4 = (v & 31) * 4;
            const float4 f = Wv[v];
            const int c = k >> 3, off = k & 7;
            w_s[sw(n4 + 0, c) + off] = f2bf(f.x);
            w_s[sw(n4 + 1, c) + off] = f2bf(f.y);
            w_s[sw(n4 + 2, c) + off] = f2bf(f.z);
            w_s[sw(n4 + 3, c) + off] = f2bf(f.w);
        }
        __syncthreads();

        const int wave = tid >> 6, lane = tid & 63;
        const int quad = lane >> 4, l16 = lane & 15;
        const int r0 = wave * 32 + l16;

        floatx4 acc[2][8];
        #pragma unroll
        for (int m = 0; m < 2; m++)
            #pragma unroll
            for (int nt = 0; nt < 8; nt++) acc[m][nt] = (floatx4){0.f, 0.f, 0.f, 0.f};

        #pragma unroll
        for (int kk = 0; kk < 4; kk++) {
            const int c = kk * 4 + quad;
            short8 af0 = *(const short8*)(&a_s[sw(r0, c)]);
            short8 af1 = *(const short8*)(&a_s[sw(r0 + 16, c)]);
            #pragma unroll
            for (int nt = 0; nt < 8; nt++) {
                short8 bf = *(const short8*)(&w_s[sw(nt * 16 + l16, c)]);
                acc[0][nt] = __builtin_amdgcn_mfma_f32_16x16x32_bf16(af0, bf, acc[0][nt], 0, 0, 0);
                acc[1][nt] = __builtin_amdgcn_mfma_f32_16x16x32_bf16(af1, bf, acc[1][nt], 0, 0, 0);
            }
        }
        // write out: C/D row=quad*4+r, col=nt*16+l16
        if (is_ue) {
            float* __restrict__ outp = hu_ws + (size_t)blk * 128 * H_;
            #pragma unroll
            for (int m = 0; m < 2; m++) {
                const int rowb = wave * 32 + m * 16 + quad * 4;
                #pragma unroll
                for (int nt = 0; nt < 8; nt++) {
                    const int col = nt * 16 + l16;
                    #pragma unroll
                    for (int r = 0; r < 4; r++)
                        outp[(size_t)(rowb + r) * H_ + col] = acc[m][nt][r];
                }
            }
        } else {
            unsigned short* __restrict__ outp = ht_bf + (size_t)(blk - 8) * 128 * H_;
            #pragma unroll
            for (int m = 0; m < 2; m++) {
                const int rowb = wave * 32 + m * 16 + quad * 4;
                #pragma unroll
                for (int nt = 0; nt < 8; nt++) {
                    const int col = nt * 16 + l16;
                    #pragma unroll
                    for (int r = 0; r < 4; r++)
                        outp[(size_t)(rowb + r) * H_ + col] = f2bf(acc[m][nt][r]);
                }
            }
        }
    } else if (blk < 28) {
        __shared__ float ge_s[2][E_];
        const int rbase = (blk - 24) * 2;
        const int half = tid >> 7, n = tid & 127;
        ge_s[half][n] = ge[(rbase + half) * E_ + n];
        __syncthreads();
        const float* __restrict__ W1g = W1 + 2 * E_ * H_;
        float acc = b1[n];
        #pragma unroll 8
        for (int e = 0; e < E_; e++)
            acc = __builtin_fmaf(ge_s[half][e], W1g[e * H_ + n], acc);
        gu_ws[(rbase + half) * H_ + n] = acc;
    } else {
        // W2 (k-major) -> w2t (n-major) bf16
        const int base = (blk - 28) * 2048;
        #pragma unroll
        for (int i = 0; i < 8; i++) {
            const int o = base + tid + i * 256;
            const int n = o >> 7, k = o & 127;
            w2t_ws[o] = f2bf(W2[k * H_ + n]);
        }
    }
}

// ---------------- Stage 2: fused gelu -> @W2 -> gelu -> @W3 ----------------
// 256 threads, 128-row t-tile; wave = two 16-row m-tiles; ht staged via LDS.
__global__ __launch_bounds__(256, 2) void stage2_kernel(
    const float* __restrict__ hu_ws, const unsigned short* __restrict__ ht_bf,
    const float* __restrict__ gu_ws,
    const unsigned short* __restrict__ w2t_ws,
    const float* __restrict__ b2, const float* __restrict__ W3,
    const float* __restrict__ b3, float* __restrict__ out)
{
    __shared__ unsigned short w2s[128 * 128];
    __shared__ unsigned short ht_s[128 * 128];
    __shared__ float hu_s[H_];
    __shared__ float b2_s[H_];
    __shared__ float w3_s[H_];

    const int tid = threadIdx.x;
    const int t0 = blockIdx.x * 128;
    const int u  = blockIdx.y;
    const int b  = blockIdx.z;

    // stage W2T (coalesced ushort8 -> swizzled b128 writes)
    #pragma unroll
    for (int i = 0; i < 8; i++) {
        const int v = tid + i * 256;
        const int n = v >> 4, c = v & 15;
        *(ushortx8*)(&w2s[sw(n, c)]) = *(const ushortx8*)(w2t_ws + n * 128 + c * 8);
    }
    // stage ht tile (coalesced)
    const unsigned short* __restrict__ htg = ht_bf + ((size_t)(b * T_ + t0)) * H_;
    #pragma unroll
    for (int i = 0; i < 8; i++) {
        const int v = tid + i * 256;
        const int row = v >> 4, c = v & 15;
        *(ushortx8*)(&ht_s[sw(row, c)]) = *(const ushortx8*)(htg + row * 128 + c * 8);
    }
    if (tid < H_) {
        hu_s[tid] = hu_ws[((b << 7) + u) * H_ + tid] + gu_ws[b * H_ + tid];
        b2_s[tid] = b2[tid];
        w3_s[tid] = W3[tid];
    }
    __syncthreads();

    const int wave = tid >> 6, lane = tid & 63;
    const int quad = lane >> 4, l16 = lane & 15;
    const int r0 = wave * 32 + l16;

    floatx4 acc[2][8];
    #pragma unroll
    for (int m = 0; m < 2; m++)
        #pragma unroll
        for (int nt = 0; nt < 8; nt++) acc[m][nt] = (floatx4){0.f, 0.f, 0.f, 0.f};

    #pragma unroll
    for (int kk = 0; kk < 4; kk++) {
        const int c = kk * 4 + quad;
        const int k0 = c << 3;
        ushortx8 u0 = *(const ushortx8*)(&ht_s[sw(r0, c)]);
        ushortx8 u1 = *(const ushortx8*)(&ht_s[sw(r0 + 16, c)]);
        const float4 h0 = *(const float4*)(&hu_s[k0]);
        const float4 h1 = *(const float4*)(&hu_s[k0 + 4]);
        const float hv[8] = {h0.x, h0.y, h0.z, h0.w, h1.x, h1.y, h1.z, h1.w};
        short8 af0, af1;
        #pragma unroll
        for (int j = 0; j < 8; j++) {
            af0[j] = (short)f2bf(gelu_fast(bf2f(u0[j]) + hv[j]));
            af1[j] = (short)f2bf(gelu_fast(bf2f(u1[j]) + hv[j]));
        }
        #pragma unroll
        for (int nt = 0; nt < 8; nt++) {
            short8 bf = *(const short8*)(&w2s[sw(nt * 16 + l16, c)]);
            acc[0][nt] = __builtin_amdgcn_mfma_f32_16x16x32_bf16(af0, bf, acc[0][nt], 0, 0, 0);
            acc[1][nt] = __builtin_amdgcn_mfma_f32_16x16x32_bf16(af1, bf, acc[1][nt], 0, 0, 0);
        }
    }

    // epilogue: +b2, gelu, *W3, reduce 128 cols/row, +b3
    const float b3v = b3[0];
    float psum[2][4] = {{0.f, 0.f, 0.f, 0.f}, {0.f, 0.f, 0.f, 0.f}};
    #pragma unroll
    for (int nt = 0; nt < 8; nt++) {
        const int n = nt * 16 + l16;
        const float bb = b2_s[n];
        const float ww = w3_s[n];
        #pragma unroll
        for (int m = 0; m < 2; m++)
            #pragma unroll
            for (int r = 0; r < 4; r++)
                psum[m][r] += gelu_fast(acc[m][nt][r] + bb) * ww;
    }
    #pragma unroll
    for (int s = 8; s >= 1; s >>= 1) {
        #pragma unroll
        for (int m = 0; m < 2; m++)
            #pragma unroll
            for (int r = 0; r < 4; r++)
                psum[m][r] += __shfl_xor(psum[m][r], s, 64);
    }
    if (l16 == 0) {
        #pragma unroll
        for (int m = 0; m < 2; m++) {
            const int rowb = t0 + wave * 32 + m * 16 + quad * 4;
            float4 o = make_float4(psum[m][0] + b3v, psum[m][1] + b3v,
                                   psum[m][2] + b3v, psum[m][3] + b3v);
            *(float4*)(out + (size_t)((b << 7) + u) * T_ + rowb) = o;
        }
    }
}

extern "C" void kernel_launch(void* const* d_in, const int* in_sizes, int n_in,
                              void* d_out, int out_size, void* d_ws, size_t ws_size,
                              hipStream_t stream)
{
    const float* ue = (const float*)d_in[0];
    const float* te = (const float*)d_in[1];
    const float* ge = (const float*)d_in[2];
    const float* W1 = (const float*)d_in[3];
    const float* b1 = (const float*)d_in[4];
    const float* W2 = (const float*)d_in[5];
    const float* b2 = (const float*)d_in[6];
    const float* W3 = (const float*)d_in[7];
    const float* b3 = (const float*)d_in[8];
    float* out = (float*)d_out;

    char* ws = (char*)d_ws;
    float* hu_ws = (float*)ws;                                     // 512 KB
    unsigned short* ht_bf = (unsigned short*)(ws + 512 * 1024);    // 512 KB
    unsigned short* w2t_ws = (unsigned short*)(ws + 1024 * 1024);  // 32 KB
    float* gu_ws = (float*)(ws + 1056 * 1024);                     // 4 KB

    stage1_kernel<<<dim3(36), dim3(256), 0, stream>>>(
        ue, te, ge, W1, b1, W2, hu_ws, ht_bf, gu_ws, w2t_ws);
    stage2_kernel<<<dim3(T_ / 128, U_, B_), dim3(256), 0, stream>>>(
        hu_ws, ht_bf, gu_ws, w2t_ws, b2, W3, b3, out);
}

// Round 5
// 99.157 us; speedup vs baseline: 1.0607x; 1.0607x over previous
//
#include <hip/hip_runtime.h>
#include <hip/hip_bf16.h>
#include <math.h>

#define E_ 128
#define H_ 128
#define B_ 8
#define U_ 128
#define T_ 256

typedef short short8 __attribute__((ext_vector_type(8)));
typedef unsigned short ushortx8 __attribute__((ext_vector_type(8)));
typedef float floatx4 __attribute__((ext_vector_type(4)));

__device__ __forceinline__ unsigned short f2bf(float f) {
    union { __hip_bfloat16 b; unsigned short u; } cv;
    cv.b = __float2bfloat16(f);
    return cv.u;
}
__device__ __forceinline__ float bf2f(unsigned short u) {
    union { unsigned int u; float f; } cv;
    cv.u = ((unsigned int)u) << 16;
    return cv.f;
}

// Swizzled LDS index for [128][128] bf16 tiles, 8-element column blocks.
__device__ __forceinline__ int sw(int row, int cblk) {
    return row * 128 + (((cblk ^ (row & 15)) << 3));
}

// tanh-form gelu: x * sigmoid(1.59577x + 0.0713548x^3); |err| vs erf-gelu <~3e-4.
__device__ __forceinline__ float gelu_fast(float x) {
    float x2 = x * x;
    float p = x * __builtin_fmaf(x2, 0.1029407583f, 2.3022586210f);  // * log2(e)
    float e = __builtin_amdgcn_exp2f(-p);
    return x * __builtin_amdgcn_rcpf(1.0f + e);
}

// ht fragment-order index: F(t_flat, k) = ((t>>4)*16 + (k>>3))*128 + (t&15)*8 + (k&7)
// A wave's MFMA A-fragment load (16 rows x 8 k) is then 16 lanes x 16B contiguous.

// ---------------- Stage 1 (one kernel, 36 blocks) ---------------------------
// blk 0..7  : hu[128 rows] = ue_tile @ W1u  (bf16 MFMA, fp32 row-major out)
// blk 8..23 : ht[128 rows] = te_tile @ W1t  (bf16 MFMA, bf16 FRAGMENT-ORDER out)
// blk 24..27: gu[2 rows]   = ge @ W1g + b1  (fp32 VALU)
// blk 28..35: w2t bf16 transpose
__global__ __launch_bounds__(256) void stage1_kernel(
    const float* __restrict__ ue, const float* __restrict__ te,
    const float* __restrict__ ge, const float* __restrict__ W1,
    const float* __restrict__ b1, const float* __restrict__ W2,
    float* __restrict__ hu_ws, unsigned short* __restrict__ ht_frag,
    float* __restrict__ gu_ws, unsigned short* __restrict__ w2t_ws)
{
    const int blk = blockIdx.x;
    const int tid = threadIdx.x;

    if (blk < 24) {
        __shared__ unsigned short a_s[128 * 128];
        __shared__ unsigned short w_s[128 * 128];
        const float* __restrict__ A;
        const float* __restrict__ W;
        const bool is_ue = (blk < 8);
        if (is_ue) { A = ue + (size_t)blk * 128 * E_;       W = W1; }
        else       { A = te + (size_t)(blk - 8) * 128 * E_; W = W1 + E_ * H_; }

        const float4* __restrict__ Av = (const float4*)A;
        #pragma unroll
        for (int i = 0; i < 16; i++) {
            const int v = tid + i * 256;
            const int row = v >> 5, c4 = (v & 31) * 4;
            const float4 f = Av[v];
            ushort4 u4 = make_ushort4(f2bf(f.x), f2bf(f.y), f2bf(f.z), f2bf(f.w));
            *(ushort4*)(&a_s[sw(row, c4 >> 3) + (c4 & 7)]) = u4;
        }
        const float4* __restrict__ Wv = (const float4*)W;
        #pragma unroll
        for (int i = 0; i < 16; i++) {
            const int v = tid + i * 256;
            const int k = v >> 5, n4 = (v & 31) * 4;
            const float4 f = Wv[v];
            const int c = k >> 3, off = k & 7;
            w_s[sw(n4 + 0, c) + off] = f2bf(f.x);
            w_s[sw(n4 + 1, c) + off] = f2bf(f.y);
            w_s[sw(n4 + 2, c) + off] = f2bf(f.z);
            w_s[sw(n4 + 3, c) + off] = f2bf(f.w);
        }
        __syncthreads();

        const int wave = tid >> 6, lane = tid & 63;
        const int quad = lane >> 4, l16 = lane & 15;
        const int r0 = wave * 32 + l16;

        floatx4 acc[2][8];
        #pragma unroll
        for (int m = 0; m < 2; m++)
            #pragma unroll
            for (int nt = 0; nt < 8; nt++) acc[m][nt] = (floatx4){0.f, 0.f, 0.f, 0.f};

        #pragma unroll
        for (int kk = 0; kk < 4; kk++) {
            const int c = kk * 4 + quad;
            short8 af0 = *(const short8*)(&a_s[sw(r0, c)]);
            short8 af1 = *(const short8*)(&a_s[sw(r0 + 16, c)]);
            #pragma unroll
            for (int nt = 0; nt < 8; nt++) {
                short8 bf = *(const short8*)(&w_s[sw(nt * 16 + l16, c)]);
                acc[0][nt] = __builtin_amdgcn_mfma_f32_16x16x32_bf16(af0, bf, acc[0][nt], 0, 0, 0);
                acc[1][nt] = __builtin_amdgcn_mfma_f32_16x16x32_bf16(af1, bf, acc[1][nt], 0, 0, 0);
            }
        }
        // C/D layout: row = quad*4 + r, col = nt*16 + l16
        if (is_ue) {
            float* __restrict__ outp = hu_ws + (size_t)blk * 128 * H_;
            #pragma unroll
            for (int m = 0; m < 2; m++) {
                const int rowb = wave * 32 + m * 16 + quad * 4;
                #pragma unroll
                for (int nt = 0; nt < 8; nt++) {
                    const int col = nt * 16 + l16;
                    #pragma unroll
                    for (int r = 0; r < 4; r++)
                        outp[(size_t)(rowb + r) * H_ + col] = acc[m][nt][r];
                }
            }
        } else {
            // fragment-order write: t_flat = (blk-8)*128 + wave*32 + m*16 + quad*4 + r
            //                       k      = nt*16 + l16
            const int tg_base = (blk - 8) * 8 + (tid >> 6) * 2;  // (t_flat>>4) base
            #pragma unroll
            for (int m = 0; m < 2; m++) {
                #pragma unroll
                for (int nt = 0; nt < 8; nt++) {
                    const size_t base = ((size_t)(tg_base + m) * 16 + nt * 2 + (l16 >> 3)) * 128
                                      + (l16 & 7);
                    #pragma unroll
                    for (int r = 0; r < 4; r++)
                        ht_frag[base + (quad * 4 + r) * 8] = f2bf(acc[m][nt][r]);
                }
            }
        }
    } else if (blk < 28) {
        __shared__ float ge_s[2][E_];
        const int rbase = (blk - 24) * 2;
        const int half = tid >> 7, n = tid & 127;
        ge_s[half][n] = ge[(rbase + half) * E_ + n];
        __syncthreads();
        const float* __restrict__ W1g = W1 + 2 * E_ * H_;
        float acc = b1[n];
        #pragma unroll 8
        for (int e = 0; e < E_; e++)
            acc = __builtin_fmaf(ge_s[half][e], W1g[e * H_ + n], acc);
        gu_ws[(rbase + half) * H_ + n] = acc;
    } else {
        const int base = (blk - 28) * 2048;
        #pragma unroll
        for (int i = 0; i < 8; i++) {
            const int o = base + tid + i * 256;
            const int n = o >> 7, k = o & 127;
            w2t_ws[o] = f2bf(W2[k * H_ + n]);
        }
    }
}

// ---------------- Stage 2: fused gelu -> @W2 -> gelu -> @W3 ----------------
// 256 threads, 128-row t-tile, wave = two 16-row m-tiles.
// A-fragments load straight from global (fragment-order, coalesced, L2-hot).
// LDS = W2 only (34 KB) -> 4 blocks/CU.
__global__ __launch_bounds__(256, 4) void stage2_kernel(
    const float* __restrict__ hu_ws, const unsigned short* __restrict__ ht_frag,
    const float* __restrict__ gu_ws,
    const unsigned short* __restrict__ w2t_ws,
    const float* __restrict__ b2, const float* __restrict__ W3,
    const float* __restrict__ b3, float* __restrict__ out)
{
    __shared__ unsigned short w2s[128 * 128];
    __shared__ float hu_s[H_];
    __shared__ float b2_s[H_];
    __shared__ float w3_s[H_];

    const int tid = threadIdx.x;
    const int t0 = blockIdx.x * 128;
    const int u  = blockIdx.y;
    const int b  = blockIdx.z;

    #pragma unroll
    for (int i = 0; i < 8; i++) {
        const int v = tid + i * 256;
        const int n = v >> 4, c = v & 15;
        *(ushortx8*)(&w2s[sw(n, c)]) = *(const ushortx8*)(w2t_ws + n * 128 + c * 8);
    }
    if (tid < H_) {
        hu_s[tid] = hu_ws[((b << 7) + u) * H_ + tid] + gu_ws[b * H_ + tid];
        b2_s[tid] = b2[tid];
        w3_s[tid] = W3[tid];
    }
    __syncthreads();

    const int wave = tid >> 6, lane = tid & 63;
    const int quad = lane >> 4, l16 = lane & 15;

    // A-fragment pointers: tg = (b*T + t0 + wave*32 + m*16) >> 4
    const int tg0 = ((b * T_ + t0) >> 4) + wave * 2;
    const unsigned short* __restrict__ hp0 =
        ht_frag + ((size_t)tg0 * 16 + quad) * 128 + l16 * 8;
    const unsigned short* __restrict__ hp1 = hp0 + 16 * 128;

    floatx4 acc[2][8];
    #pragma unroll
    for (int m = 0; m < 2; m++)
        #pragma unroll
        for (int nt = 0; nt < 8; nt++) acc[m][nt] = (floatx4){0.f, 0.f, 0.f, 0.f};

    // double-buffered A loads across kk (stride between kk chunks: 4*128 shorts)
    ushortx8 c0 = *(const ushortx8*)hp0;
    ushortx8 c1 = *(const ushortx8*)hp1;

    #pragma unroll
    for (int kk = 0; kk < 4; kk++) {
        ushortx8 n0, n1;
        if (kk < 3) {
            n0 = *(const ushortx8*)(hp0 + (kk + 1) * 512);
            n1 = *(const ushortx8*)(hp1 + (kk + 1) * 512);
        }
        const int k0 = kk * 32 + quad * 8;
        const float4 h0 = *(const float4*)(&hu_s[k0]);
        const float4 h1 = *(const float4*)(&hu_s[k0 + 4]);
        const float hv[8] = {h0.x, h0.y, h0.z, h0.w, h1.x, h1.y, h1.z, h1.w};
        short8 af0, af1;
        #pragma unroll
        for (int j = 0; j < 8; j++) {
            af0[j] = (short)f2bf(gelu_fast(bf2f(c0[j]) + hv[j]));
            af1[j] = (short)f2bf(gelu_fast(bf2f(c1[j]) + hv[j]));
        }
        const int c = kk * 4 + quad;
        #pragma unroll
        for (int nt = 0; nt < 8; nt++) {
            short8 bf = *(const short8*)(&w2s[sw(nt * 16 + l16, c)]);
            acc[0][nt] = __builtin_amdgcn_mfma_f32_16x16x32_bf16(af0, bf, acc[0][nt], 0, 0, 0);
            acc[1][nt] = __builtin_amdgcn_mfma_f32_16x16x32_bf16(af1, bf, acc[1][nt], 0, 0, 0);
        }
        c0 = n0; c1 = n1;
    }

    // epilogue: +b2, gelu, *W3, reduce 128 cols/row, +b3
    const float b3v = b3[0];
    float psum[2][4] = {{0.f, 0.f, 0.f, 0.f}, {0.f, 0.f, 0.f, 0.f}};
    #pragma unroll
    for (int nt = 0; nt < 8; nt++) {
        const int n = nt * 16 + l16;
        const float bb = b2_s[n];
        const float ww = w3_s[n];
        #pragma unroll
        for (int m = 0; m < 2; m++)
            #pragma unroll
            for (int r = 0; r < 4; r++)
                psum[m][r] += gelu_fast(acc[m][nt][r] + bb) * ww;
    }
    #pragma unroll
    for (int s = 8; s >= 1; s >>= 1) {
        #pragma unroll
        for (int m = 0; m < 2; m++)
            #pragma unroll
            for (int r = 0; r < 4; r++)
                psum[m][r] += __shfl_xor(psum[m][r], s, 64);
    }
    if (l16 == 0) {
        #pragma unroll
        for (int m = 0; m < 2; m++) {
            const int rowb = t0 + wave * 32 + m * 16 + quad * 4;
            float4 o = make_float4(psum[m][0] + b3v, psum[m][1] + b3v,
                                   psum[m][2] + b3v, psum[m][3] + b3v);
            *(float4*)(out + (size_t)((b << 7) + u) * T_ + rowb) = o;
        }
    }
}

extern "C" void kernel_launch(void* const* d_in, const int* in_sizes, int n_in,
                              void* d_out, int out_size, void* d_ws, size_t ws_size,
                              hipStream_t stream)
{
    const float* ue = (const float*)d_in[0];
    const float* te = (const float*)d_in[1];
    const float* ge = (const float*)d_in[2];
    const float* W1 = (const float*)d_in[3];
    const float* b1 = (const float*)d_in[4];
    const float* W2 = (const float*)d_in[5];
    const float* b2 = (const float*)d_in[6];
    const float* W3 = (const float*)d_in[7];
    const float* b3 = (const float*)d_in[8];
    float* out = (float*)d_out;

    char* ws = (char*)d_ws;
    float* hu_ws = (float*)ws;                                     // 512 KB
    unsigned short* ht_frag = (unsigned short*)(ws + 512 * 1024);  // 512 KB
    unsigned short* w2t_ws = (unsigned short*)(ws + 1024 * 1024);  // 32 KB
    float* gu_ws = (float*)(ws + 1056 * 1024);                     // 4 KB

    stage1_kernel<<<dim3(36), dim3(256), 0, stream>>>(
        ue, te, ge, W1, b1, W2, hu_ws, ht_frag, gu_ws, w2t_ws);
    stage2_kernel<<<dim3(T_ / 128, U_, B_), dim3(256), 0, stream>>>(
        hu_ws, ht_frag, gu_ws, w2t_ws, b2, W3, b3, out);
}